// Round 1
// baseline (1744.522 us; speedup 1.0000x reference)
//
#include <hip/hip_runtime.h>
#include <math.h>

#define B_ 2
#define N_ 6
#define D_ 59
#define FH 32
#define FW 88
#define C_ 80
#define NX 360
#define NY 360
// NZ = 1
#define P_PER_B (N_*D_*FH*FW)     // 996,864
#define NPTS (B_*P_PER_B)         // 1,993,728
#define NCELL (NX*NY)             // 129,600
#define TOT (NPTS*C_)             // 159,498,240

// Static device scratch (no reliance on ws_size); all fully rewritten each launch.
__device__ float g_inv[B_*N_*16];
__device__ int   g_idx[NPTS];
__device__ float g_grid[B_*NCELL*C_];   // layout (b, x, y, c) — channel-minor

// ---- 1) invert the 12 lidar2img matrices (f64 Gauss-Jordan w/ partial pivot, round to f32)
__global__ void k_inv(const float* __restrict__ l2i) {
  int m = threadIdx.x;
  if (m >= B_*N_) return;
  double a[4][4], inv[4][4];
  for (int i=0;i<4;i++) for (int j=0;j<4;j++){
    a[i][j] = (double)l2i[m*16+i*4+j];
    inv[i][j] = (i==j)?1.0:0.0;
  }
  for (int k=0;k<4;k++){
    int p=k; double mx=fabs(a[k][k]);
    for (int r=k+1;r<4;r++){ double v=fabs(a[r][k]); if (v>mx){mx=v;p=r;} }
    if (p!=k){
      for (int j=0;j<4;j++){
        double t=a[k][j]; a[k][j]=a[p][j]; a[p][j]=t;
        t=inv[k][j]; inv[k][j]=inv[p][j]; inv[p][j]=t;
      }
    }
    double pi = 1.0/a[k][k];
    for (int j=0;j<4;j++){ a[k][j]*=pi; inv[k][j]*=pi; }
    for (int r=0;r<4;r++) if (r!=k){
      double f=a[r][k];
      for (int j=0;j<4;j++){ a[r][j]-=f*a[k][j]; inv[r][j]-=f*inv[k][j]; }
    }
  }
  for (int i=0;i<4;i++) for (int j=0;j<4;j++)
    g_inv[m*16+i*4+j] = (float)inv[i][j];
}

// ---- 2) per-point geometry -> cell index (or -1). f32, no fp contraction (match numpy).
__global__ void k_geom(const float* __restrict__ itrans, const float* __restrict__ iscale) {
#pragma clang fp contract(off)
  int p = blockIdx.x*blockDim.x + threadIdx.x;
  if (p >= NPTS) return;
  int b  = p / P_PER_B;
  int r  = p - b*P_PER_B;
  int n  = r / (D_*FH*FW);
  int r2 = r - n*(D_*FH*FW);
  int d  = r2 / (FH*FW);
  int r3 = r2 - d*(FH*FW);
  int h  = r3 / FW;
  int w  = r3 - h*FW;
  int bn = b*N_ + n;

  // frustum (linspace computed in f64 then rounded, matching np.linspace)
  float xw = (float)((double)w * (703.0/87.0));
  float yh = (float)((double)h * (255.0/31.0));
  float dd = (float)(d + 1);               // ds = 1..59

  float t0 = itrans[bn*3+0], t1 = itrans[bn*3+1], t2 = itrans[bn*3+2];
  float s  = iscale[bn];

  float px = xw + t0, py = yh + t1, pd = dd + t2;
  float x0 = px / s, x1 = py / s;
  float p0 = x0*pd, p1 = x1*pd, p2 = pd;

  const float* iv = &g_inv[bn*16];
  float gx = ((iv[0]*p0 + iv[1]*p1) + iv[2]*p2)  + iv[3]*1.0f;
  float gy = ((iv[4]*p0 + iv[5]*p1) + iv[6]*p2)  + iv[7]*1.0f;
  float gz = ((iv[8]*p0 + iv[9]*p1) + iv[10]*p2) + iv[11]*1.0f;

  // (geom - (bx - dx/2)) / dx ; bx-dx/2 rounds to exactly {-54,-54,-10} in f32
  int vx = (int)((gx + 54.0f) / 0.3f);   // trunc toward zero == astype(int32)
  int vy = (int)((gy + 54.0f) / 0.3f);
  int vz = (int)((gz + 10.0f) / 20.0f);

  bool ok = (vx>=0) & (vx<NX) & (vy>=0) & (vy<NY) & (vz>=0) & (vz<1);
  g_idx[p] = ok ? ((b*NCELL + vx*NY + vy)*C_) : -1;
}

// ---- 3) zero the accumulator
__global__ void k_zero() {
  int i = blockIdx.x*blockDim.x + threadIdx.x;     // over float4s: 5,184,000
  ((float4*)g_grid)[i] = make_float4(0.f,0.f,0.f,0.f);
}

// ---- 4) scatter: one float4 of feats per thread (coalesced reads), 4 atomics to contiguous addrs
__global__ void k_scatter(const float* __restrict__ feats) {
  int t = blockIdx.x*256 + threadIdx.x;            // < 39,874,560 (exact)
  int point = t / 20;
  int c4 = (t - point*20) * 4;
  int base = g_idx[point];
  if (base >= 0) {
    float4 v = ((const float4*)feats)[t];
    float* p = &g_grid[base + c4];
    atomicAdd(p+0, v.x);
    atomicAdd(p+1, v.y);
    atomicAdd(p+2, v.z);
    atomicAdd(p+3, v.w);
  }
}

// ---- 5) transpose (b,xy,c) -> (b,c,xy), LDS-tiled 64 cells x 80 ch, pad 81
__global__ void k_transpose(float* __restrict__ out) {
  __shared__ float lds[64*81];
  int bi = blockIdx.x;
  int b = bi / 2025;
  int tile = bi - b*2025;
  int cell0 = tile * 64;
  int tid = threadIdx.x;
  const float* src = &g_grid[(b*NCELL + cell0)*C_];
  #pragma unroll
  for (int it=0; it<20; ++it) {
    int t = it*256 + tid;
    int cl = t/80, cc = t - cl*80;
    lds[cl*81 + cc] = src[t];
  }
  __syncthreads();
  float* dst = &out[(size_t)b*C_*NCELL + cell0];
  #pragma unroll
  for (int it=0; it<20; ++it) {
    int t = it*256 + tid;
    int cc = t >> 6, xy = t & 63;
    dst[(size_t)cc*NCELL + xy] = lds[xy*81 + cc];
  }
}

extern "C" void kernel_launch(void* const* d_in, const int* in_sizes, int n_in,
                              void* d_out, int out_size, void* d_ws, size_t ws_size,
                              hipStream_t stream) {
  const float* feats  = (const float*)d_in[0];
  const float* itrans = (const float*)d_in[1];
  const float* iscale = (const float*)d_in[2];
  const float* l2i    = (const float*)d_in[3];
  float* out = (float*)d_out;

  k_inv<<<1, 16, 0, stream>>>(l2i);
  k_geom<<<(NPTS + 255)/256, 256, 0, stream>>>(itrans, iscale);
  k_zero<<<5184000/256, 256, 0, stream>>>();                 // 20,250 blocks
  k_scatter<<<39874560/256, 256, 0, stream>>>(feats);        // 155,760 blocks
  k_transpose<<<B_*2025, 256, 0, stream>>>(out);             // 4,050 blocks
}

// Round 2
// 313.551 us; speedup vs baseline: 5.5638x; 5.5638x over previous
//
#include <hip/hip_runtime.h>
#include <math.h>

#define B_ 2
#define N_ 6
#define D_ 59
#define FH 32
#define FW 88
#define C_ 80
#define NX 360
#define NY 360
// NZ = 1
#define P_PER_B (N_*D_*FH*FW)     // 996,864
#define NPTS (B_*P_PER_B)         // 1,993,728  (divisible by 16)
#define NCELL (NX*NY)             // 129,600
#define NCHUNK (NPTS/16)          // 124,608
#define SCAT_THREADS (NCHUNK*20)  // 2,492,160 = 9735 * 256 exactly

// Static device scratch; fully rewritten every launch (graph/replay safe).
__device__ float g_inv[B_*N_*16];
__device__ int   g_idx[NPTS];
__device__ float g_grid[B_*NCELL*C_];   // layout (b, x, y, c) — channel-minor

// ---- 1) invert the 12 lidar2img matrices (f64 Gauss-Jordan w/ partial pivot, round to f32)
__global__ void k_inv(const float* __restrict__ l2i) {
  int m = threadIdx.x;
  if (m >= B_*N_) return;
  double a[4][4], inv[4][4];
  for (int i=0;i<4;i++) for (int j=0;j<4;j++){
    a[i][j] = (double)l2i[m*16+i*4+j];
    inv[i][j] = (i==j)?1.0:0.0;
  }
  for (int k=0;k<4;k++){
    int p=k; double mx=fabs(a[k][k]);
    for (int r=k+1;r<4;r++){ double v=fabs(a[r][k]); if (v>mx){mx=v;p=r;} }
    if (p!=k){
      for (int j=0;j<4;j++){
        double t=a[k][j]; a[k][j]=a[p][j]; a[p][j]=t;
        t=inv[k][j]; inv[k][j]=inv[p][j]; inv[p][j]=t;
      }
    }
    double pi = 1.0/a[k][k];
    for (int j=0;j<4;j++){ a[k][j]*=pi; inv[k][j]*=pi; }
    for (int r=0;r<4;r++) if (r!=k){
      double f=a[r][k];
      for (int j=0;j<4;j++){ a[r][j]-=f*a[k][j]; inv[r][j]-=f*inv[k][j]; }
    }
  }
  for (int i=0;i<4;i++) for (int j=0;j<4;j++)
    g_inv[m*16+i*4+j] = (float)inv[i][j];
}

// ---- 2) per-point geometry -> scaled cell base index (or -1). f32, no fp contraction.
__global__ void k_geom(const float* __restrict__ itrans, const float* __restrict__ iscale) {
#pragma clang fp contract(off)
  int p = blockIdx.x*blockDim.x + threadIdx.x;
  if (p >= NPTS) return;
  int b  = p / P_PER_B;
  int r  = p - b*P_PER_B;
  int n  = r / (D_*FH*FW);
  int r2 = r - n*(D_*FH*FW);
  int d  = r2 / (FH*FW);
  int r3 = r2 - d*(FH*FW);
  int h  = r3 / FW;
  int w  = r3 - h*FW;
  int bn = b*N_ + n;

  float xw = (float)((double)w * (703.0/87.0));   // np.linspace in f64, rounded
  float yh = (float)((double)h * (255.0/31.0));
  float dd = (float)(d + 1);                      // ds = 1..59

  float t0 = itrans[bn*3+0], t1 = itrans[bn*3+1], t2 = itrans[bn*3+2];
  float s  = iscale[bn];

  float px = xw + t0, py = yh + t1, pd = dd + t2;
  float x0 = px / s, x1 = py / s;
  float p0 = x0*pd, p1 = x1*pd, p2 = pd;

  const float* iv = &g_inv[bn*16];
  float gx = ((iv[0]*p0 + iv[1]*p1) + iv[2]*p2)  + iv[3]*1.0f;
  float gy = ((iv[4]*p0 + iv[5]*p1) + iv[6]*p2)  + iv[7]*1.0f;
  float gz = ((iv[8]*p0 + iv[9]*p1) + iv[10]*p2) + iv[11]*1.0f;

  int vx = (int)((gx + 54.0f) / 0.3f);   // trunc toward zero == astype(int32)
  int vy = (int)((gy + 54.0f) / 0.3f);
  int vz = (int)((gz + 10.0f) / 20.0f);

  bool ok = (vx>=0) & (vx<NX) & (vy>=0) & (vy<NY) & (vz>=0) & (vz<1);
  g_idx[p] = ok ? ((b*NCELL + vx*NY + vy)*C_) : -1;
}

// ---- 3) zero the accumulator (float4s: 5,184,000)
__global__ void k_zero() {
  int i = blockIdx.x*blockDim.x + threadIdx.x;
  ((float4*)g_grid)[i] = make_float4(0.f,0.f,0.f,0.f);
}

// ---- 4) run-collapsed scatter: thread = (16-point chunk, c4 channel-group).
// Consecutive valid points share cells in runs; accumulate in-register, one
// float4-group atomic burst per run break instead of per point.
__global__ void k_scatter(const float* __restrict__ feats) {
  int t = blockIdx.x*256 + threadIdx.x;            // < SCAT_THREADS (exact)
  int chunk = t / 20;
  int c4 = t - chunk*20;

  int idx[16];
  const int4* idx4 = (const int4*)g_idx;
  #pragma unroll
  for (int k=0;k<4;++k) {
    int4 v = idx4[chunk*4 + k];
    idx[k*4+0]=v.x; idx[k*4+1]=v.y; idx[k*4+2]=v.z; idx[k*4+3]=v.w;
  }

  const float4* f4 = (const float4*)feats;
  int pbase = chunk*16*20 + c4;                    // float4-unit index

  float4 acc = make_float4(0.f,0.f,0.f,0.f);
  int cur = -1;
  #pragma unroll
  for (int j=0;j<16;++j) {
    int id = idx[j];
    if (id != cur) {
      if (cur >= 0) {
        float* p = &g_grid[cur + c4*4];
        atomicAdd(p+0,acc.x); atomicAdd(p+1,acc.y);
        atomicAdd(p+2,acc.z); atomicAdd(p+3,acc.w);
      }
      cur = id;
      acc = make_float4(0.f,0.f,0.f,0.f);
    }
    if (id >= 0) {
      float4 v = f4[pbase + j*20];
      acc.x+=v.x; acc.y+=v.y; acc.z+=v.z; acc.w+=v.w;
    }
  }
  if (cur >= 0) {
    float* p = &g_grid[cur + c4*4];
    atomicAdd(p+0,acc.x); atomicAdd(p+1,acc.y);
    atomicAdd(p+2,acc.z); atomicAdd(p+3,acc.w);
  }
}

// ---- 5) transpose (b,xy,c) -> (b,c,xy), LDS-tiled 64 cells x 80 ch, pad 81
__global__ void k_transpose(float* __restrict__ out) {
  __shared__ float lds[64*81];
  int bi = blockIdx.x;
  int b = bi / 2025;
  int tile = bi - b*2025;
  int cell0 = tile * 64;
  int tid = threadIdx.x;
  const float* src = &g_grid[(b*NCELL + cell0)*C_];
  #pragma unroll
  for (int it=0; it<20; ++it) {
    int t = it*256 + tid;
    int cl = t/80, cc = t - cl*80;
    lds[cl*81 + cc] = src[t];
  }
  __syncthreads();
  float* dst = &out[(size_t)b*C_*NCELL + cell0];
  #pragma unroll
  for (int it=0; it<20; ++it) {
    int t = it*256 + tid;
    int cc = t >> 6, xy = t & 63;
    dst[(size_t)cc*NCELL + xy] = lds[xy*81 + cc];
  }
}

extern "C" void kernel_launch(void* const* d_in, const int* in_sizes, int n_in,
                              void* d_out, int out_size, void* d_ws, size_t ws_size,
                              hipStream_t stream) {
  const float* feats  = (const float*)d_in[0];
  const float* itrans = (const float*)d_in[1];
  const float* iscale = (const float*)d_in[2];
  const float* l2i    = (const float*)d_in[3];
  float* out = (float*)d_out;

  k_inv<<<1, 16, 0, stream>>>(l2i);
  k_geom<<<(NPTS + 255)/256, 256, 0, stream>>>(itrans, iscale);
  k_zero<<<5184000/256, 256, 0, stream>>>();                 // 20,250 blocks
  k_scatter<<<SCAT_THREADS/256, 256, 0, stream>>>(feats);    // 9,735 blocks
  k_transpose<<<B_*2025, 256, 0, stream>>>(out);             // 4,050 blocks
}